// Round 2
// baseline (2669.143 us; speedup 1.0000x reference)
//
#include <hip/hip_runtime.h>
#include <math.h>

#define Bc 16
#define Lc 2048
#define BLc (Bc*Lc)

__device__ __forceinline__ float softplusf(float v) {
    return (v > 20.f) ? v : log1pf(__expf(v));
}
__device__ __forceinline__ float siluf(float v) {
    return v / (1.f + __expf(-v));
}

__global__ __launch_bounds__(256) void zero_kernel(float* p, int n) {
    int i = blockIdx.x * 256 + threadIdx.x;
    if (i < n) p[i] = 0.f;
}

// C[m,n] = act(bias[n] + sum_k A[arow(m)*lda+k] * W[n*K+k])
// arow(m) = (m>>logCL)*bRS + l0 + (m & (CL-1));  local layout: bRS=CL, l0=0 -> arow=m
// act: 0=none, 1=softplus
__global__ __launch_bounds__(256) void gemm_nt(
    const float* __restrict__ A, int lda, int bRS, int l0, int logCL,
    const float* __restrict__ W,
    float* __restrict__ C,
    const float* __restrict__ bias, int act,
    int N, int K)
{
    __shared__ float As[16][68];   // pad 68: float4-aligned rows, <=2-way banks (free)
    __shared__ float Ws[16][68];
    const int m0 = blockIdx.y * 64;
    const int n0 = blockIdx.x * 64;
    const int tid = threadIdx.x;
    const int tx = tid & 15, ty = tid >> 4;
    const int clm = (1 << logCL) - 1;

    float acc[4][4] = {};

    for (int k0 = 0; k0 < K; k0 += 16) {
        #pragma unroll
        for (int r = 0; r < 4; ++r) {
            int lin = tid + r * 256;           // 0..1023
            int k = lin & 15, mm = lin >> 4;   // k 0..15, mm 0..63
            int m = m0 + mm;
            int arow = ((m >> logCL) * bRS) + l0 + (m & clm);
            As[k][mm] = A[(size_t)arow * lda + k0 + k];
            int n = n0 + mm;
            Ws[k][mm] = (n < N) ? W[(size_t)n * K + k0 + k] : 0.f;
        }
        __syncthreads();
        #pragma unroll
        for (int kk = 0; kk < 16; ++kk) {
            float4 av = *(const float4*)&As[kk][ty * 4];
            float4 bv = *(const float4*)&Ws[kk][tx * 4];
            float a_[4] = {av.x, av.y, av.z, av.w};
            float b_[4] = {bv.x, bv.y, bv.z, bv.w};
            #pragma unroll
            for (int i = 0; i < 4; ++i)
                #pragma unroll
                for (int j = 0; j < 4; ++j)
                    acc[i][j] += a_[i] * b_[j];
        }
        __syncthreads();
    }

    #pragma unroll
    for (int i = 0; i < 4; ++i) {
        int m = m0 + ty * 4 + i;
        #pragma unroll
        for (int j = 0; j < 4; ++j) {
            int n = n0 + tx * 4 + j;
            if (n < N) {
                float v = acc[i][j];
                if (bias) v += bias[n];
                if (act == 1) v = softplusf(v);
                C[(size_t)m * N + n] = v;
            }
        }
    }
}

// depthwise causal conv (width 4) + SiLU, chunk-local with halo carry
__global__ __launch_bounds__(256) void conv_silu(
    const float* __restrict__ xcC, const float* __restrict__ carry,
    const float* __restrict__ cw, const float* __restrict__ cb,
    float* __restrict__ uC, int logCL)
{
    int idx = blockIdx.x * 256 + threadIdx.x;   // [0, M*512)
    int e = idx & 511;
    int row = idx >> 9;                 // b*CL + ll
    int ll = row & ((1 << logCL) - 1);
    int b = row >> logCL;
    float acc = cb[e];
    #pragma unroll
    for (int k = 0; k < 4; ++k) {
        int j = ll + k - 3;
        float xv;
        if (j >= 0) xv = xcC[(size_t)(row + k - 3) * 512 + e];
        else        xv = carry[(size_t)(b * 3 + (j + 3)) * 512 + e];  // zeros at chunk 0
        acc += xv * cw[e * 4 + k];
    }
    uC[idx] = siluf(acc);
}

// save last 3 xc rows per batch for next chunk's conv halo
__global__ __launch_bounds__(256) void carry_save(
    const float* __restrict__ xcC, float* __restrict__ carry, int CL)
{
    int idx = blockIdx.x * 256 + threadIdx.x;   // [0, 16*3*512)
    int e = idx & 511;
    int t = idx >> 9;                            // b*3 + i
    int b = t / 3, i = t - 3 * b;
    carry[idx] = xcC[(size_t)(b * CL + CL - 3 + i) * 512 + e];
}

// selective scan chunk: lane per (b,d,s); h persisted in hbuf across chunks
__global__ __launch_bounds__(256) void scan_kernel(
    const float* __restrict__ dtC, const float* __restrict__ uC,
    const float* __restrict__ dbcC, const float* __restrict__ zC,
    const float* __restrict__ A_log, const float* __restrict__ Dv,
    float* __restrict__ hbuf, float* __restrict__ yC, int CL)
{
    const int g = threadIdx.x >> 5;                 // d within block (0..7)
    const int s = threadIdx.x & 31;                 // state index
    const int b = blockIdx.x >> 6;                  // 0..15
    const int d = ((blockIdx.x & 63) << 3) + g;     // 0..511

    const float a_coef = -__expf(A_log[d * 32 + s]);
    const float Dd = Dv[d];
    const size_t hidx = ((size_t)(b * 512 + d)) * 32 + s;
    float h = hbuf[hidx];

    size_t off512 = ((size_t)b * CL) * 512 + d;
    size_t off80  = ((size_t)b * CL) * 80;

    for (int l = 0; l < CL; ++l) {
        float dtv = dtC[off512];
        float uv  = uC[off512];
        float Bv  = dbcC[off80 + 16 + s];
        float Cv  = dbcC[off80 + 48 + s];
        h = h * __expf(dtv * a_coef) + dtv * uv * Bv;
        float p = h * Cv;
        #pragma unroll
        for (int o = 16; o; o >>= 1) p += __shfl_xor(p, o, 32);
        if (s == 0) {
            float zv = zC[off512];
            yC[off512] = (p + uv * Dd) * siluf(zv);
        }
        off512 += 512; off80 += 80;
    }
    hbuf[hidx] = h;
}

// fused MLP head per (b,l) row
__global__ __launch_bounds__(256) void ff_kernel(
    const float* __restrict__ mo,
    const float* __restrict__ W1, const float* __restrict__ b1,
    const float* __restrict__ W2, const float* __restrict__ b2,
    float* __restrict__ out, int l0, int logCL)
{
    __shared__ float row[256];
    __shared__ float h2[32];
    const int idx = blockIdx.x;                  // chunk-local row
    const int tid = threadIdx.x;
    row[tid] = mo[(size_t)idx * 256 + tid];
    __syncthreads();

    const int j = tid >> 3, p = tid & 7;
    float acc = 0.f;
    const int kbase = p * 32;
    #pragma unroll
    for (int k = 0; k < 32; ++k) acc += row[kbase + k] * W1[j * 256 + kbase + k];
    #pragma unroll
    for (int o = 1; o < 8; o <<= 1) acc += __shfl_xor(acc, o, 8);
    if (p == 0) {
        float v = acc + b1[j];
        h2[j] = (v > 0.f) ? v : 0.01f * v;
    }
    __syncthreads();

    float a2 = b2[tid];
    #pragma unroll
    for (int jj = 0; jj < 32; ++jj) a2 += h2[jj] * W2[tid * 32 + jj];

    const int clm = (1 << logCL) - 1;
    const size_t orow = ((size_t)(idx >> logCL)) * Lc + l0 + (idx & clm);
    out[orow * 256 + tid] = 1.f / (1.f + __expf(-a2));
}

extern "C" void kernel_launch(void* const* d_in, const int* in_sizes, int n_in,
                              void* d_out, int out_size, void* d_ws, size_t ws_size,
                              hipStream_t stream) {
    const float* x      = (const float*)d_in[0];
    const float* W_in   = (const float*)d_in[1];
    const float* conv_w = (const float*)d_in[2];
    const float* conv_b = (const float*)d_in[3];
    const float* W_xproj= (const float*)d_in[4];
    const float* W_dt   = (const float*)d_in[5];
    const float* b_dt   = (const float*)d_in[6];
    const float* A_log  = (const float*)d_in[7];
    const float* Dv     = (const float*)d_in[8];
    const float* W_out  = (const float*)d_in[9];
    const float* W_ff1  = (const float*)d_in[10];
    const float* b_ff1  = (const float*)d_in[11];
    const float* W_ff2  = (const float*)d_in[12];
    const float* b_ff2  = (const float*)d_in[13];
    float* out = (float*)d_out;

    // pick fewest chunks that fit ws: bytes = (286720 + M*2128)*4, M = BL/NC
    int NC = 32;
    for (int c = 1; c <= 32; c <<= 1) {
        size_t M = (size_t)BLc / c;
        size_t need = (286720ull + M * 2128ull) * 4ull;
        if (need <= ws_size) { NC = c; break; }
    }
    const int CL = Lc / NC;
    int logCL = 0; while ((1 << logCL) < CL) ++logCL;
    const size_t M = (size_t)BLc / NC;

    float* ws = (float*)d_ws;
    float* hbuf  = ws;                       // 16*512*32 = 262144
    float* carry = hbuf + 262144;            // 16*3*512  = 24576
    float* xcC   = carry + 24576;            // M*512  (reused as yC)
    float* zC    = xcC + M * 512;            // M*512
    float* uC    = zC  + M * 512;            // M*512  (reused as moC)
    float* dtC   = uC  + M * 512;            // M*512
    float* dbcC  = dtC + M * 512;            // M*80
    float* yC = xcC;
    float* moC = uC;

    dim3 blk(256);

    zero_kernel<<<(286720 + 255) / 256, blk, 0, stream>>>(ws, 286720);

    for (int c = 0; c < NC; ++c) {
        const int l0 = c * CL;

        // xz = x @ W_in.T (two halves)
        gemm_nt<<<dim3(8, M / 64), blk, 0, stream>>>(x, 256, Lc, l0, logCL, W_in,             xcC, nullptr, 0, 512, 256);
        gemm_nt<<<dim3(8, M / 64), blk, 0, stream>>>(x, 256, Lc, l0, logCL, W_in + 512 * 256, zC,  nullptr, 0, 512, 256);

        // u = silu(conv4(xc)+cb); then save halo for next chunk
        conv_silu<<<(M * 512) / 256, blk, 0, stream>>>(xcC, carry, conv_w, conv_b, uC, logCL);
        carry_save<<<96, blk, 0, stream>>>(xcC, carry, CL);

        // dbc = u @ W_xproj.T  [dt_lo 16 | B 32 | C 32]
        gemm_nt<<<dim3(2, M / 64), blk, 0, stream>>>(uC, 512, CL, 0, logCL, W_xproj, dbcC, nullptr, 0, 80, 512);

        // dt = softplus(dt_lo @ W_dt.T + b_dt)
        gemm_nt<<<dim3(8, M / 64), blk, 0, stream>>>(dbcC, 80, CL, 0, logCL, W_dt, dtC, b_dt, 1, 512, 16);

        // selective scan (fused +u*D, *silu(z)); y overwrites xcC
        scan_kernel<<<1024, blk, 0, stream>>>(dtC, uC, dbcC, zC, A_log, Dv, hbuf, yC, CL);

        // mo = y @ W_out.T
        gemm_nt<<<dim3(4, M / 64), blk, 0, stream>>>(yC, 512, CL, 0, logCL, W_out, moC, nullptr, 0, 256, 512);

        // MLP head
        ff_kernel<<<M, blk, 0, stream>>>(moC, W_ff1, b_ff1, W_ff2, b_ff2, out, l0, logCL);
    }
}

// Round 3
// 1331.072 us; speedup vs baseline: 2.0053x; 2.0053x over previous
//
#include <hip/hip_runtime.h>
#include <math.h>

#define Bc 16
#define Lc 2048
#define BLc (Bc*Lc)
#define NSUB 16
#define HN 262144   // 16*512*32 state lanes

__device__ __forceinline__ float softplusf(float v) {
    return (v > 20.f) ? v : log1pf(__expf(v));
}
__device__ __forceinline__ float siluf(float v) {
    return v / (1.f + __expf(-v));
}

__global__ __launch_bounds__(256) void zero_kernel(float* p, int n) {
    int i = blockIdx.x * 256 + threadIdx.x;
    if (i < n) p[i] = 0.f;
}

// C[m,n] = act(bias[n] + sum_k A[arow(m)*lda+k] * W[n*K+k])
__global__ __launch_bounds__(256) void gemm_nt(
    const float* __restrict__ A, int lda, int bRS, int l0, int logCL,
    const float* __restrict__ W,
    float* __restrict__ C,
    const float* __restrict__ bias, int act,
    int N, int K)
{
    __shared__ float As[16][68];
    __shared__ float Ws[16][68];
    const int m0 = blockIdx.y * 64;
    const int n0 = blockIdx.x * 64;
    const int tid = threadIdx.x;
    const int tx = tid & 15, ty = tid >> 4;
    const int clm = (1 << logCL) - 1;

    float acc[4][4] = {};

    for (int k0 = 0; k0 < K; k0 += 16) {
        #pragma unroll
        for (int r = 0; r < 4; ++r) {
            int lin = tid + r * 256;
            int k = lin & 15, mm = lin >> 4;
            int m = m0 + mm;
            int arow = ((m >> logCL) * bRS) + l0 + (m & clm);
            As[k][mm] = A[(size_t)arow * lda + k0 + k];
            int n = n0 + mm;
            Ws[k][mm] = (n < N) ? W[(size_t)n * K + k0 + k] : 0.f;
        }
        __syncthreads();
        #pragma unroll
        for (int kk = 0; kk < 16; ++kk) {
            float4 av = *(const float4*)&As[kk][ty * 4];
            float4 bv = *(const float4*)&Ws[kk][tx * 4];
            float a_[4] = {av.x, av.y, av.z, av.w};
            float b_[4] = {bv.x, bv.y, bv.z, bv.w};
            #pragma unroll
            for (int i = 0; i < 4; ++i)
                #pragma unroll
                for (int j = 0; j < 4; ++j)
                    acc[i][j] += a_[i] * b_[j];
        }
        __syncthreads();
    }

    #pragma unroll
    for (int i = 0; i < 4; ++i) {
        int m = m0 + ty * 4 + i;
        #pragma unroll
        for (int j = 0; j < 4; ++j) {
            int n = n0 + tx * 4 + j;
            if (n < N) {
                float v = acc[i][j];
                if (bias) v += bias[n];
                if (act == 1) v = softplusf(v);
                C[(size_t)m * N + n] = v;
            }
        }
    }
}

// depthwise causal conv (width 4) + SiLU, chunk-local with halo carry
__global__ __launch_bounds__(256) void conv_silu(
    const float* __restrict__ xcC, const float* __restrict__ carry,
    const float* __restrict__ cw, const float* __restrict__ cb,
    float* __restrict__ uC, int logCL)
{
    int idx = blockIdx.x * 256 + threadIdx.x;
    int e = idx & 511;
    int row = idx >> 9;
    int ll = row & ((1 << logCL) - 1);
    int b = row >> logCL;
    float acc = cb[e];
    #pragma unroll
    for (int k = 0; k < 4; ++k) {
        int j = ll + k - 3;
        float xv;
        if (j >= 0) xv = xcC[(size_t)(row + k - 3) * 512 + e];
        else        xv = carry[(size_t)(b * 3 + (j + 3)) * 512 + e];
        acc += xv * cw[e * 4 + k];
    }
    uC[idx] = siluf(acc);
}

__global__ __launch_bounds__(256) void carry_save(
    const float* __restrict__ xcC, float* __restrict__ carry, int CL)
{
    int idx = blockIdx.x * 256 + threadIdx.x;
    int e = idx & 511;
    int t = idx >> 9;
    int b = t / 3, i = t - 3 * b;
    carry[idx] = xcC[(size_t)(b * CL + CL - 3 + i) * 512 + e];
}

// ---- scan pass 1: per-subchunk local scan from h=0; store end state + decay product
// lane = (b, d, c); all 32 states in registers; decay product via exp(acoef * sum(dt))
__global__ __launch_bounds__(256) void scan_pass1(
    const float* __restrict__ dtC, const float* __restrict__ uC,
    const float* __restrict__ dbcC, const float* __restrict__ A_log,
    float* __restrict__ aprodB, float* __restrict__ hendB,
    int CL, int Lch)
{
    const int t = threadIdx.x;
    const int bi = blockIdx.x;
    const int c  = bi & (NSUB - 1);
    const int dh = (bi >> 4) & 1;
    const int b  = bi >> 5;
    const int d  = dh * 256 + t;

    float acoef[32];
    #pragma unroll
    for (int g = 0; g < 8; ++g) {
        float4 al = *(const float4*)&A_log[d * 32 + 4 * g];
        acoef[4*g+0] = -__expf(al.x);
        acoef[4*g+1] = -__expf(al.y);
        acoef[4*g+2] = -__expf(al.z);
        acoef[4*g+3] = -__expf(al.w);
    }

    float h[32];
    #pragma unroll
    for (int s = 0; s < 32; ++s) h[s] = 0.f;
    float dtsum = 0.f;

    size_t row = (size_t)b * CL + (size_t)c * Lch;
    size_t off = row * 512 + d;
    size_t r80 = row * 80;
    for (int j = 0; j < Lch; ++j) {
        float dtv = dtC[off];
        float uv  = uC[off];
        float dtu = dtv * uv;
        dtsum += dtv;
        #pragma unroll
        for (int g = 0; g < 8; ++g) {
            float4 Bv = *(const float4*)&dbcC[r80 + 16 + 4 * g];
            float a0 = __expf(dtv * acoef[4*g+0]);
            float a1 = __expf(dtv * acoef[4*g+1]);
            float a2 = __expf(dtv * acoef[4*g+2]);
            float a3 = __expf(dtv * acoef[4*g+3]);
            h[4*g+0] = a0 * h[4*g+0] + dtu * Bv.x;
            h[4*g+1] = a1 * h[4*g+1] + dtu * Bv.y;
            h[4*g+2] = a2 * h[4*g+2] + dtu * Bv.z;
            h[4*g+3] = a3 * h[4*g+3] + dtu * Bv.w;
        }
        off += 512; r80 += 80;
    }

    size_t o = (size_t)c * HN + ((size_t)(b * 512 + d)) * 32;
    #pragma unroll
    for (int g = 0; g < 8; ++g) {
        *(float4*)&hendB[o + 4 * g] =
            make_float4(h[4*g+0], h[4*g+1], h[4*g+2], h[4*g+3]);
        *(float4*)&aprodB[o + 4 * g] =
            make_float4(__expf(acoef[4*g+0] * dtsum), __expf(acoef[4*g+1] * dtsum),
                        __expf(acoef[4*g+2] * dtsum), __expf(acoef[4*g+3] * dtsum));
    }
}

// ---- fixup: chain subchunk states sequentially per (b,d,s); also advance hbuf carry
__global__ __launch_bounds__(256) void scan_fixup(
    const float* __restrict__ aprodB, const float* __restrict__ hendB,
    float* __restrict__ hinitB, float* __restrict__ hbuf)
{
    int idx = blockIdx.x * 256 + threadIdx.x;   // [0, HN)
    float h = hbuf[idx];
    #pragma unroll
    for (int c = 0; c < NSUB; ++c) {
        size_t o = (size_t)c * HN + idx;
        hinitB[o] = h;
        h = aprodB[o] * h + hendB[o];
    }
    hbuf[idx] = h;
}

// ---- scan pass 2: re-scan from correct h_init, emit y (fused +u*D, *silu(z))
__global__ __launch_bounds__(256) void scan_pass2(
    const float* __restrict__ dtC, const float* __restrict__ uC,
    const float* __restrict__ dbcC, const float* __restrict__ zC,
    const float* __restrict__ A_log, const float* __restrict__ Dv,
    const float* __restrict__ hinitB, float* __restrict__ yC,
    int CL, int Lch)
{
    const int t = threadIdx.x;
    const int bi = blockIdx.x;
    const int c  = bi & (NSUB - 1);
    const int dh = (bi >> 4) & 1;
    const int b  = bi >> 5;
    const int d  = dh * 256 + t;

    float acoef[32];
    #pragma unroll
    for (int g = 0; g < 8; ++g) {
        float4 al = *(const float4*)&A_log[d * 32 + 4 * g];
        acoef[4*g+0] = -__expf(al.x);
        acoef[4*g+1] = -__expf(al.y);
        acoef[4*g+2] = -__expf(al.z);
        acoef[4*g+3] = -__expf(al.w);
    }
    const float Dd = Dv[d];

    float h[32];
    size_t o = (size_t)c * HN + ((size_t)(b * 512 + d)) * 32;
    #pragma unroll
    for (int g = 0; g < 8; ++g) {
        float4 hv = *(const float4*)&hinitB[o + 4 * g];
        h[4*g+0] = hv.x; h[4*g+1] = hv.y; h[4*g+2] = hv.z; h[4*g+3] = hv.w;
    }

    size_t row = (size_t)b * CL + (size_t)c * Lch;
    size_t off = row * 512 + d;
    size_t r80 = row * 80;
    for (int j = 0; j < Lch; ++j) {
        float dtv = dtC[off];
        float uv  = uC[off];
        float zv  = zC[off];
        float dtu = dtv * uv;
        float y = 0.f;
        #pragma unroll
        for (int g = 0; g < 8; ++g) {
            float4 Bv = *(const float4*)&dbcC[r80 + 16 + 4 * g];
            float4 Cv = *(const float4*)&dbcC[r80 + 48 + 4 * g];
            float a0 = __expf(dtv * acoef[4*g+0]);
            float a1 = __expf(dtv * acoef[4*g+1]);
            float a2 = __expf(dtv * acoef[4*g+2]);
            float a3 = __expf(dtv * acoef[4*g+3]);
            h[4*g+0] = a0 * h[4*g+0] + dtu * Bv.x;
            h[4*g+1] = a1 * h[4*g+1] + dtu * Bv.y;
            h[4*g+2] = a2 * h[4*g+2] + dtu * Bv.z;
            h[4*g+3] = a3 * h[4*g+3] + dtu * Bv.w;
            y += h[4*g+0] * Cv.x;
            y += h[4*g+1] * Cv.y;
            y += h[4*g+2] * Cv.z;
            y += h[4*g+3] * Cv.w;
        }
        yC[off] = (y + uv * Dd) * siluf(zv);
        off += 512; r80 += 80;
    }
}

// fused MLP head per (b,l) row
__global__ __launch_bounds__(256) void ff_kernel(
    const float* __restrict__ mo,
    const float* __restrict__ W1, const float* __restrict__ b1,
    const float* __restrict__ W2, const float* __restrict__ b2,
    float* __restrict__ out, int l0, int logCL)
{
    __shared__ float row[256];
    __shared__ float h2[32];
    const int idx = blockIdx.x;
    const int tid = threadIdx.x;
    row[tid] = mo[(size_t)idx * 256 + tid];
    __syncthreads();

    const int j = tid >> 3, p = tid & 7;
    float acc = 0.f;
    const int kbase = p * 32;
    #pragma unroll
    for (int k = 0; k < 32; ++k) acc += row[kbase + k] * W1[j * 256 + kbase + k];
    #pragma unroll
    for (int o = 1; o < 8; o <<= 1) acc += __shfl_xor(acc, o, 8);
    if (p == 0) {
        float v = acc + b1[j];
        h2[j] = (v > 0.f) ? v : 0.01f * v;
    }
    __syncthreads();

    float a2 = b2[tid];
    #pragma unroll
    for (int jj = 0; jj < 32; ++jj) a2 += h2[jj] * W2[tid * 32 + jj];

    const int clm = (1 << logCL) - 1;
    const size_t orow = ((size_t)(idx >> logCL)) * Lc + l0 + (idx & clm);
    out[orow * 256 + tid] = 1.f / (1.f + __expf(-a2));
}

extern "C" void kernel_launch(void* const* d_in, const int* in_sizes, int n_in,
                              void* d_out, int out_size, void* d_ws, size_t ws_size,
                              hipStream_t stream) {
    const float* x      = (const float*)d_in[0];
    const float* W_in   = (const float*)d_in[1];
    const float* conv_w = (const float*)d_in[2];
    const float* conv_b = (const float*)d_in[3];
    const float* W_xproj= (const float*)d_in[4];
    const float* W_dt   = (const float*)d_in[5];
    const float* b_dt   = (const float*)d_in[6];
    const float* A_log  = (const float*)d_in[7];
    const float* Dv     = (const float*)d_in[8];
    const float* W_out  = (const float*)d_in[9];
    const float* W_ff1  = (const float*)d_in[10];
    const float* b_ff1  = (const float*)d_in[11];
    const float* W_ff2  = (const float*)d_in[12];
    const float* b_ff2  = (const float*)d_in[13];
    float* out = (float*)d_out;

    // fit: persistent (hbuf+carry) + 3 scan bufs (NSUB*HN each) + pipeline M*2128
    int NC = 32;
    for (int c = 1; c <= 32; c <<= 1) {
        size_t M = (size_t)BLc / c;
        size_t need = (286720ull + 3ull * NSUB * HN + M * 2128ull) * 4ull;
        if (need <= ws_size) { NC = c; break; }
    }
    const int CL = Lc / NC;
    int logCL = 0; while ((1 << logCL) < CL) ++logCL;
    const int Lch = CL / NSUB;
    const size_t M = (size_t)BLc / NC;

    float* ws = (float*)d_ws;
    float* hbuf   = ws;                        // 262144
    float* carry  = hbuf + 262144;             // 24576
    float* aprodB = carry + 24576;             // NSUB*HN
    float* hendB  = aprodB + (size_t)NSUB * HN;
    float* hinitB = hendB  + (size_t)NSUB * HN;
    float* xcC    = hinitB + (size_t)NSUB * HN; // M*512 (reused as yC)
    float* zC     = xcC + M * 512;
    float* uC     = zC  + M * 512;              // reused as moC
    float* dtC    = uC  + M * 512;
    float* dbcC   = dtC + M * 512;              // M*80
    float* yC  = xcC;
    float* moC = uC;

    dim3 blk(256);

    zero_kernel<<<(286720 + 255) / 256, blk, 0, stream>>>(ws, 286720);

    for (int c = 0; c < NC; ++c) {
        const int l0 = c * CL;

        gemm_nt<<<dim3(8, M / 64), blk, 0, stream>>>(x, 256, Lc, l0, logCL, W_in,             xcC, nullptr, 0, 512, 256);
        gemm_nt<<<dim3(8, M / 64), blk, 0, stream>>>(x, 256, Lc, l0, logCL, W_in + 512 * 256, zC,  nullptr, 0, 512, 256);

        conv_silu<<<(M * 512) / 256, blk, 0, stream>>>(xcC, carry, conv_w, conv_b, uC, logCL);
        carry_save<<<96, blk, 0, stream>>>(xcC, carry, CL);

        gemm_nt<<<dim3(2, M / 64), blk, 0, stream>>>(uC, 512, CL, 0, logCL, W_xproj, dbcC, nullptr, 0, 80, 512);
        gemm_nt<<<dim3(8, M / 64), blk, 0, stream>>>(dbcC, 80, CL, 0, logCL, W_dt, dtC, b_dt, 1, 512, 16);

        // two-pass chunk-parallel selective scan
        scan_pass1<<<Bc * 2 * NSUB, blk, 0, stream>>>(dtC, uC, dbcC, A_log, aprodB, hendB, CL, Lch);
        scan_fixup<<<HN / 256, blk, 0, stream>>>(aprodB, hendB, hinitB, hbuf);
        scan_pass2<<<Bc * 2 * NSUB, blk, 0, stream>>>(dtC, uC, dbcC, zC, A_log, Dv, hinitB, yC, CL, Lch);

        gemm_nt<<<dim3(4, M / 64), blk, 0, stream>>>(yC, 512, CL, 0, logCL, W_out, moC, nullptr, 0, 256, 512);

        ff_kernel<<<M, blk, 0, stream>>>(moC, W_ff1, b_ff1, W_ff2, b_ff2, out, l0, logCL);
    }
}

// Round 4
// 680.759 us; speedup vs baseline: 3.9208x; 1.9553x over previous
//
#include <hip/hip_runtime.h>
#include <math.h>

#define Bc 16
#define Lc 2048
#define BLc (Bc*Lc)
#define NSUB 16
#define HN 262144   // 16*512*32 state lanes

typedef __attribute__((ext_vector_type(8))) short bf16x8;
typedef __attribute__((ext_vector_type(4))) float f32x4;

__device__ __forceinline__ float softplusf(float v) {
    return (v > 20.f) ? v : log1pf(__expf(v));
}
__device__ __forceinline__ float siluf(float v) {
    return v / (1.f + __expf(-v));
}
__device__ __forceinline__ unsigned short f2b(float f) {   // RNE f32->bf16
    union { float f; unsigned u; } v; v.f = f;
    unsigned r = v.u + 0x7FFFu + ((v.u >> 16) & 1u);
    return (unsigned short)(r >> 16);
}
__device__ __forceinline__ float b2f(unsigned short b) {
    union { unsigned u; float f; } v; v.u = ((unsigned)b) << 16;
    return v.f;
}

__global__ __launch_bounds__(256) void zero_kernel(float* p, int n) {
    int i = blockIdx.x * 256 + threadIdx.x;
    if (i < n) p[i] = 0.f;
}

__global__ __launch_bounds__(256) void cvt_bf16(const float* __restrict__ s,
                                                unsigned short* __restrict__ d, int n) {
    int i = blockIdx.x * 256 + threadIdx.x;
    if (i < n) d[i] = f2b(s[i]);
}

// ---------------- bf16 MFMA GEMM (NT): C[m,n] = act(bias[n] + sum_k A[arow(m)][k]*W[n][k])
// block = 4 waves, each wave 64x64 out (4x4 MFMA tiles); no LDS, direct-global fragments.
// arow(m) = (m>>logCL)*aRS + al0 + (m&clm); orow(m) = (m>>logCL)*oRS + ol0 + (m&clm).
// act: 0 none, 1 leaky_relu(0.01), 2 sigmoid. Output to outF (f32) or outB (bf16).
__global__ __launch_bounds__(256) void gemm_mfma(
    const unsigned short* __restrict__ A, int K, int aRS, int al0,
    const unsigned short* __restrict__ W,
    float* __restrict__ outF, unsigned short* __restrict__ outB,
    const float* __restrict__ bias, int act,
    int oRS, int ol0, int logCL, int N)
{
    const int lane = threadIdx.x & 63;
    const int w = threadIdx.x >> 6;
    const int wr = w >> 1, wc = w & 1;
    const int m_base = blockIdx.y * 128 + wr * 64;
    const int n_base = blockIdx.x * 128 + wc * 64;
    if (n_base >= N) return;                      // wave-uniform, no barriers in kernel
    const int r = lane & 15, q = lane >> 4;
    const int clm = (1 << logCL) - 1;

    int ntiles = (N - n_base + 15) >> 4; if (ntiles > 4) ntiles = 4;

    const unsigned short* aptr[4];
    #pragma unroll
    for (int mi = 0; mi < 4; ++mi) {
        int m = m_base + mi * 16 + r;
        int arow = ((m >> logCL) * aRS) + al0 + (m & clm);
        aptr[mi] = A + (size_t)arow * K + q * 8;
    }
    const unsigned short* bptr[4];
    #pragma unroll
    for (int ni = 0; ni < 4; ++ni) {
        int nt = n_base + ni * 16;
        bptr[ni] = W + (size_t)((nt < N) ? (nt + r) : 0) * K + q * 8;
    }

    f32x4 acc[4][4];
    #pragma unroll
    for (int mi = 0; mi < 4; ++mi)
        #pragma unroll
        for (int ni = 0; ni < 4; ++ni)
            acc[mi][ni] = (f32x4){0.f, 0.f, 0.f, 0.f};

    for (int k0 = 0; k0 < K; k0 += 32) {
        bf16x8 a[4], b[4];
        #pragma unroll
        for (int mi = 0; mi < 4; ++mi) a[mi] = *(const bf16x8*)(aptr[mi] + k0);
        #pragma unroll
        for (int ni = 0; ni < 4; ++ni) if (ni < ntiles) b[ni] = *(const bf16x8*)(bptr[ni] + k0);
        #pragma unroll
        for (int mi = 0; mi < 4; ++mi)
            #pragma unroll
            for (int ni = 0; ni < 4; ++ni)
                if (ni < ntiles)
                    acc[mi][ni] = __builtin_amdgcn_mfma_f32_16x16x32_bf16(a[mi], b[ni], acc[mi][ni], 0, 0, 0);
    }

    #pragma unroll
    for (int ni = 0; ni < 4; ++ni) {
        if (ni >= ntiles) continue;
        int n = n_base + ni * 16 + r;
        float bs = bias ? bias[n] : 0.f;
        #pragma unroll
        for (int mi = 0; mi < 4; ++mi) {
            #pragma unroll
            for (int rr = 0; rr < 4; ++rr) {
                int m = m_base + mi * 16 + q * 4 + rr;
                float v = acc[mi][ni][rr] + bs;
                if (act == 1) v = (v > 0.f) ? v : 0.01f * v;
                else if (act == 2) v = 1.f / (1.f + __expf(-v));
                size_t orow = ((size_t)(m >> logCL)) * oRS + ol0 + (m & clm);
                if (outF) outF[orow * N + n] = v;
                else      outB[orow * N + n] = f2b(v);
            }
        }
    }
}

// ---------------- fp32 tiled GEMM (kept for the K=16 dt projection)
__global__ __launch_bounds__(256) void gemm_nt(
    const float* __restrict__ A, int lda, int bRS, int l0, int logCL,
    const float* __restrict__ W,
    float* __restrict__ C,
    const float* __restrict__ bias, int act,
    int N, int K)
{
    __shared__ float As[16][68];
    __shared__ float Ws[16][68];
    const int m0 = blockIdx.y * 64;
    const int n0 = blockIdx.x * 64;
    const int tid = threadIdx.x;
    const int tx = tid & 15, ty = tid >> 4;
    const int clm = (1 << logCL) - 1;

    float acc[4][4] = {};

    for (int k0 = 0; k0 < K; k0 += 16) {
        #pragma unroll
        for (int rr = 0; rr < 4; ++rr) {
            int lin = tid + rr * 256;
            int k = lin & 15, mm = lin >> 4;
            int m = m0 + mm;
            int arow = ((m >> logCL) * bRS) + l0 + (m & clm);
            As[k][mm] = A[(size_t)arow * lda + k0 + k];
            int n = n0 + mm;
            Ws[k][mm] = (n < N) ? W[(size_t)n * K + k0 + k] : 0.f;
        }
        __syncthreads();
        #pragma unroll
        for (int kk = 0; kk < 16; ++kk) {
            float4 av = *(const float4*)&As[kk][ty * 4];
            float4 bv = *(const float4*)&Ws[kk][tx * 4];
            float a_[4] = {av.x, av.y, av.z, av.w};
            float b_[4] = {bv.x, bv.y, bv.z, bv.w};
            #pragma unroll
            for (int i = 0; i < 4; ++i)
                #pragma unroll
                for (int j = 0; j < 4; ++j)
                    acc[i][j] += a_[i] * b_[j];
        }
        __syncthreads();
    }

    #pragma unroll
    for (int i = 0; i < 4; ++i) {
        int m = m0 + ty * 4 + i;
        #pragma unroll
        for (int j = 0; j < 4; ++j) {
            int n = n0 + tx * 4 + j;
            if (n < N) {
                float v = acc[i][j];
                if (bias) v += bias[n];
                if (act == 1) v = softplusf(v);
                C[(size_t)m * N + n] = v;
            }
        }
    }
}

// depthwise causal conv (width 4) + SiLU -> u (bf16), chunk-local with halo carry
__global__ __launch_bounds__(256) void conv_silu(
    const float* __restrict__ xcC, const float* __restrict__ carry,
    const float* __restrict__ cw, const float* __restrict__ cb,
    unsigned short* __restrict__ uB, int logCL)
{
    int idx = blockIdx.x * 256 + threadIdx.x;
    int e = idx & 511;
    int row = idx >> 9;
    int ll = row & ((1 << logCL) - 1);
    int b = row >> logCL;
    float acc = cb[e];
    #pragma unroll
    for (int k = 0; k < 4; ++k) {
        int j = ll + k - 3;
        float xv;
        if (j >= 0) xv = xcC[(size_t)(row + k - 3) * 512 + e];
        else        xv = carry[(size_t)(b * 3 + (j + 3)) * 512 + e];
        acc += xv * cw[e * 4 + k];
    }
    uB[idx] = f2b(siluf(acc));
}

__global__ __launch_bounds__(256) void carry_save(
    const float* __restrict__ xcC, float* __restrict__ carry, int CL)
{
    int idx = blockIdx.x * 256 + threadIdx.x;
    int e = idx & 511;
    int t = idx >> 9;
    int b = t / 3, i = t - 3 * b;
    carry[idx] = xcC[(size_t)(b * CL + CL - 3 + i) * 512 + e];
}

// ---- scan pass 1: per-subchunk local scan from h=0; store end state + decay product
__global__ __launch_bounds__(256) void scan_pass1(
    const float* __restrict__ dtC, const unsigned short* __restrict__ uB,
    const float* __restrict__ dbcC, const float* __restrict__ A_log,
    float* __restrict__ aprodB, float* __restrict__ hendB,
    int CL, int Lch)
{
    const int t = threadIdx.x;
    const int bi = blockIdx.x;
    const int c  = bi & (NSUB - 1);
    const int dh = (bi >> 4) & 1;
    const int b  = bi >> 5;
    const int d  = dh * 256 + t;

    float acoef[32];
    #pragma unroll
    for (int g = 0; g < 8; ++g) {
        float4 al = *(const float4*)&A_log[d * 32 + 4 * g];
        acoef[4*g+0] = -__expf(al.x);
        acoef[4*g+1] = -__expf(al.y);
        acoef[4*g+2] = -__expf(al.z);
        acoef[4*g+3] = -__expf(al.w);
    }

    float h[32];
    #pragma unroll
    for (int s = 0; s < 32; ++s) h[s] = 0.f;
    float dtsum = 0.f;

    size_t row = (size_t)b * CL + (size_t)c * Lch;
    size_t off = row * 512 + d;
    size_t r80 = row * 80;
    for (int j = 0; j < Lch; ++j) {
        float dtv = dtC[off];
        float uv  = b2f(uB[off]);
        float dtu = dtv * uv;
        dtsum += dtv;
        #pragma unroll
        for (int g = 0; g < 8; ++g) {
            float4 Bv = *(const float4*)&dbcC[r80 + 16 + 4 * g];
            float a0 = __expf(dtv * acoef[4*g+0]);
            float a1 = __expf(dtv * acoef[4*g+1]);
            float a2 = __expf(dtv * acoef[4*g+2]);
            float a3 = __expf(dtv * acoef[4*g+3]);
            h[4*g+0] = a0 * h[4*g+0] + dtu * Bv.x;
            h[4*g+1] = a1 * h[4*g+1] + dtu * Bv.y;
            h[4*g+2] = a2 * h[4*g+2] + dtu * Bv.z;
            h[4*g+3] = a3 * h[4*g+3] + dtu * Bv.w;
        }
        off += 512; r80 += 80;
    }

    size_t o = (size_t)c * HN + ((size_t)(b * 512 + d)) * 32;
    #pragma unroll
    for (int g = 0; g < 8; ++g) {
        *(float4*)&hendB[o + 4 * g] =
            make_float4(h[4*g+0], h[4*g+1], h[4*g+2], h[4*g+3]);
        *(float4*)&aprodB[o + 4 * g] =
            make_float4(__expf(acoef[4*g+0] * dtsum), __expf(acoef[4*g+1] * dtsum),
                        __expf(acoef[4*g+2] * dtsum), __expf(acoef[4*g+3] * dtsum));
    }
}

// ---- fixup: chain subchunk states per (b,d,s); hinit overwrites aprod slot in place
__global__ __launch_bounds__(256) void scan_fixup(
    float* __restrict__ aprodB, const float* __restrict__ hendB,
    float* __restrict__ hbuf)
{
    int idx = blockIdx.x * 256 + threadIdx.x;   // [0, HN)
    float h = hbuf[idx];
    #pragma unroll
    for (int c = 0; c < NSUB; ++c) {
        size_t o = (size_t)c * HN + idx;
        float a = aprodB[o];
        float e = hendB[o];
        aprodB[o] = h;           // becomes h_init for subchunk c
        h = a * h + e;
    }
    hbuf[idx] = h;
}

// ---- scan pass 2: re-scan from h_init, emit y (bf16, fused +u*D, *silu(z))
__global__ __launch_bounds__(256) void scan_pass2(
    const float* __restrict__ dtC, const unsigned short* __restrict__ uB,
    const float* __restrict__ dbcC, const unsigned short* __restrict__ zB,
    const float* __restrict__ A_log, const float* __restrict__ Dv,
    const float* __restrict__ hinitB, unsigned short* __restrict__ yB,
    int CL, int Lch)
{
    const int t = threadIdx.x;
    const int bi = blockIdx.x;
    const int c  = bi & (NSUB - 1);
    const int dh = (bi >> 4) & 1;
    const int b  = bi >> 5;
    const int d  = dh * 256 + t;

    float acoef[32];
    #pragma unroll
    for (int g = 0; g < 8; ++g) {
        float4 al = *(const float4*)&A_log[d * 32 + 4 * g];
        acoef[4*g+0] = -__expf(al.x);
        acoef[4*g+1] = -__expf(al.y);
        acoef[4*g+2] = -__expf(al.z);
        acoef[4*g+3] = -__expf(al.w);
    }
    const float Dd = Dv[d];

    float h[32];
    size_t o = (size_t)c * HN + ((size_t)(b * 512 + d)) * 32;
    #pragma unroll
    for (int g = 0; g < 8; ++g) {
        float4 hv = *(const float4*)&hinitB[o + 4 * g];
        h[4*g+0] = hv.x; h[4*g+1] = hv.y; h[4*g+2] = hv.z; h[4*g+3] = hv.w;
    }

    size_t row = (size_t)b * CL + (size_t)c * Lch;
    size_t off = row * 512 + d;
    size_t r80 = row * 80;
    for (int j = 0; j < Lch; ++j) {
        float dtv = dtC[off];
        float uv  = b2f(uB[off]);
        float zv  = b2f(zB[off]);
        float dtu = dtv * uv;
        float y = 0.f;
        #pragma unroll
        for (int g = 0; g < 8; ++g) {
            float4 Bv = *(const float4*)&dbcC[r80 + 16 + 4 * g];
            float4 Cv = *(const float4*)&dbcC[r80 + 48 + 4 * g];
            float a0 = __expf(dtv * acoef[4*g+0]);
            float a1 = __expf(dtv * acoef[4*g+1]);
            float a2 = __expf(dtv * acoef[4*g+2]);
            float a3 = __expf(dtv * acoef[4*g+3]);
            h[4*g+0] = a0 * h[4*g+0] + dtu * Bv.x;
            h[4*g+1] = a1 * h[4*g+1] + dtu * Bv.y;
            h[4*g+2] = a2 * h[4*g+2] + dtu * Bv.z;
            h[4*g+3] = a3 * h[4*g+3] + dtu * Bv.w;
            y += h[4*g+0] * Cv.x;
            y += h[4*g+1] * Cv.y;
            y += h[4*g+2] * Cv.z;
            y += h[4*g+3] * Cv.w;
        }
        yB[off] = f2b((y + uv * Dd) * siluf(zv));
        off += 512; r80 += 80;
    }
}

extern "C" void kernel_launch(void* const* d_in, const int* in_sizes, int n_in,
                              void* d_out, int out_size, void* d_ws, size_t ws_size,
                              hipStream_t stream) {
    const float* x      = (const float*)d_in[0];
    const float* W_in   = (const float*)d_in[1];
    const float* conv_w = (const float*)d_in[2];
    const float* conv_b = (const float*)d_in[3];
    const float* W_xproj= (const float*)d_in[4];
    const float* W_dt   = (const float*)d_in[5];
    const float* b_dt   = (const float*)d_in[6];
    const float* A_log  = (const float*)d_in[7];
    const float* Dv     = (const float*)d_in[8];
    const float* W_out  = (const float*)d_in[9];
    const float* W_ff1  = (const float*)d_in[10];
    const float* b_ff1  = (const float*)d_in[11];
    const float* W_ff2  = (const float*)d_in[12];
    const float* b_ff2  = (const float*)d_in[13];
    float* out = (float*)d_out;

    // fixed floats: hbuf 262144 + carry 24576 + aprod/hend 2*4194304 + x_bf16 4194304 + wts 225280
    const size_t FIXED = 262144ull + 24576 + 4194304ull * 3 + 225280;
    int NC = 32;
    for (int c = 1; c <= 32; c <<= 1) {
        size_t M = (size_t)BLc / c;
        size_t need = (FIXED + M * 1616ull) * 4ull;
        if (need <= ws_size) { NC = c; break; }
    }
    const int CL = Lc / NC;
    int logCL = 0; while ((1 << logCL) < CL) ++logCL;
    const int Lch = CL / NSUB;
    const size_t M = (size_t)BLc / NC;

    float* ws = (float*)d_ws;
    float* hbuf   = ws;                        // 262144
    float* carry  = hbuf + 262144;             // 24576
    float* aprodB = carry + 24576;             // NSUB*HN = 4194304 (reused as hinit)
    float* hendB  = aprodB + 4194304;          // 4194304
    unsigned short* xb   = (unsigned short*)(hendB + 4194304);  // BLc*256 shorts
    unsigned short* wInb = xb + (size_t)BLc * 256;              // 262144 sh
    unsigned short* wXb  = wInb + 262144;                       // 40960 sh
    unsigned short* wOb  = wXb + 40960;                         // 131072 sh
    unsigned short* wF1b = wOb + 131072;                        // 8192 sh
    unsigned short* wF2b = wF1b + 8192;                         // 8192 sh
    float* xcC  = (float*)(wF2b + 8192);       // M*512 f32
    unsigned short* zB = (unsigned short*)(xcC + M * 512);      // M*512 sh
    unsigned short* uB = zB + M * 512;                          // M*512 sh
    float* dtC  = (float*)(uB + M * 512);      // M*512 f32
    float* dbcC = dtC + M * 512;               // M*80 f32
    // aliases into xcC region (xcC dead after carry_save):
    unsigned short* yB  = (unsigned short*)xcC;            // M*512 sh
    unsigned short* moB = (unsigned short*)(xcC + M * 256);// M*256 sh
    unsigned short* hB  = (unsigned short*)(xcC + M * 384);// M*32 sh

    dim3 blk(256);

    zero_kernel<<<(286720 + 255) / 256, blk, 0, stream>>>(ws, 286720);

    // one-time bf16 conversions
    cvt_bf16<<<(BLc * 256 + 255) / 256, blk, 0, stream>>>(x, xb, BLc * 256);
    cvt_bf16<<<(262144 + 255) / 256, blk, 0, stream>>>(W_in, wInb, 262144);
    cvt_bf16<<<(40960 + 255) / 256, blk, 0, stream>>>(W_xproj, wXb, 40960);
    cvt_bf16<<<(131072 + 255) / 256, blk, 0, stream>>>(W_out, wOb, 131072);
    cvt_bf16<<<(8192 + 255) / 256, blk, 0, stream>>>(W_ff1, wF1b, 8192);
    cvt_bf16<<<(8192 + 255) / 256, blk, 0, stream>>>(W_ff2, wF2b, 8192);

    for (int c = 0; c < NC; ++c) {
        const int l0 = c * CL;

        // xz halves: xc (f32, for conv) and z (bf16, for scan gate)
        gemm_mfma<<<dim3(4, M / 128), blk, 0, stream>>>(xb, 256, Lc, l0, wInb,
            xcC, nullptr, nullptr, 0, CL, 0, logCL, 512);
        gemm_mfma<<<dim3(4, M / 128), blk, 0, stream>>>(xb, 256, Lc, l0, wInb + 512 * 256,
            nullptr, zB, nullptr, 0, CL, 0, logCL, 512);

        conv_silu<<<(M * 512) / 256, blk, 0, stream>>>(xcC, carry, conv_w, conv_b, uB, logCL);
        carry_save<<<96, blk, 0, stream>>>(xcC, carry, CL);

        // dbc = u @ W_xproj.T  [dt_lo 16 | B 32 | C 32]
        gemm_mfma<<<dim3(1, M / 128), blk, 0, stream>>>(uB, 512, CL, 0, wXb,
            dbcC, nullptr, nullptr, 0, CL, 0, logCL, 80);

        // dt = softplus(dt_lo @ W_dt.T + b_dt)  (fp32, K=16)
        gemm_nt<<<dim3(8, M / 64), blk, 0, stream>>>(dbcC, 80, CL, 0, logCL, W_dt, dtC, b_dt, 1, 512, 16);

        // two-pass chunk-parallel selective scan
        scan_pass1<<<Bc * 2 * NSUB, blk, 0, stream>>>(dtC, uB, dbcC, A_log, aprodB, hendB, CL, Lch);
        scan_fixup<<<HN / 256, blk, 0, stream>>>(aprodB, hendB, hbuf);
        scan_pass2<<<Bc * 2 * NSUB, blk, 0, stream>>>(dtC, uB, dbcC, zB, A_log, Dv, aprodB, yB, CL, Lch);

        // mo = y @ W_out.T (bf16 out for the head)
        gemm_mfma<<<dim3(2, M / 128), blk, 0, stream>>>(yB, 512, CL, 0, wOb,
            nullptr, moB, nullptr, 0, CL, 0, logCL, 256);

        // head: h = leaky(mo@W1.T + b1) ; out = sigmoid(h@W2.T + b2)
        gemm_mfma<<<dim3(1, M / 128), blk, 0, stream>>>(moB, 256, CL, 0, wF1b,
            nullptr, hB, b_ff1, 1, CL, 0, logCL, 32);
        gemm_mfma<<<dim3(2, M / 128), blk, 0, stream>>>(hB, 32, CL, 0, wF2b,
            out, nullptr, b_ff2, 2, Lc, l0, logCL, 256);
    }
}